// Round 4
// baseline (169.827 us; speedup 1.0000x reference)
//
#include <hip/hip_runtime.h>
#include <hip/hip_bf16.h>

#define BB 8
#define SS 1024
#define IN_DIM 1024
#define NOUT 1024
#define DHEAD 256
#define MTOT (BB*SS)

typedef __bf16 bf16;
typedef __bf16 bf16x8 __attribute__((ext_vector_type(8)));
typedef __bf16 bf16x4 __attribute__((ext_vector_type(4)));
typedef float f32x4 __attribute__((ext_vector_type(4)));

// ws layout (bytes)
#define QK_OFF   0                 // 8*2*2*1024*256 bf16 = 16 MiB
#define XB_OFF   (16u*1024*1024)   // 8192*1024 bf16     = 16 MiB
#define WB_OFF   (32u*1024*1024)   // 1024*1024 bf16     =  2 MiB
#define RT_OFF   (34u*1024*1024)   // 1024*128 float2    =  1 MiB
#define ACC_OFF  (35u*1024*1024)   // 2 floats

__device__ __forceinline__ void gload_lds16(const void* g, void* l) {
  __builtin_amdgcn_global_load_lds(
      (const __attribute__((address_space(1))) unsigned int*)g,
      (__attribute__((address_space(3))) unsigned int*)l, 16, 0, 0);
}

__global__ void cvt_bf16_kernel(const float* __restrict__ in, bf16* __restrict__ out, int n4) {
  int i = blockIdx.x * blockDim.x + threadIdx.x;
  if (i >= n4) return;
  float4 v = ((const float4*)in)[i];
  bf16x4 o;
  o.x = (bf16)v.x; o.y = (bf16)v.y; o.z = (bf16)v.z; o.w = (bf16)v.w;
  ((bf16x4*)out)[i] = o;
}

__global__ void rope_table_kernel(float2* __restrict__ rt) {
  int i = blockIdx.x * blockDim.x + threadIdx.x;   // S*128 = 131072
  int s = i >> 7, f = i & 127;
  float inv = __expf((float)f * (-2.70805020110221007f / 128.0f)); // 15^(-2f/256)
  float ang = (float)s * inv;
  float c, sn;
  __sincosf(ang, &sn, &c);
  rt[i] = make_float2(c, sn);
}

// C = X(bf16) @ W(bf16)^T + b, fused RoPE, write Q/K bf16 -> ws
// QK layout: [b][h][qk][s][d], qk: 0=Q 1=K
__global__ __launch_bounds__(256) void gemm_rope_kernel(
    const bf16* __restrict__ Xb, const bf16* __restrict__ Wb,
    const float* __restrict__ bias, const float2* __restrict__ rt,
    bf16* __restrict__ QK) {
  __shared__ __align__(16) bf16 lA[128 * 32];
  __shared__ __align__(16) bf16 lB[128 * 32];
  const int tid = threadIdx.x;
  const int lane = tid & 63, w = tid >> 6;
  const int wr = w >> 1, wc = w & 1;
  const int fr = lane & 15, fq = lane >> 4;
  const int m0 = blockIdx.y * 128, n0 = blockIdx.x * 128;
  const int c0 = tid, c1 = tid + 256;

  f32x4 acc[4][4] = {};

  for (int k0 = 0; k0 < IN_DIM; k0 += 32) {
    gload_lds16(Xb + (size_t)(m0 + (c0 >> 2)) * IN_DIM + k0 + (c0 & 3) * 8, &lA[c0 * 8]);
    gload_lds16(Xb + (size_t)(m0 + (c1 >> 2)) * IN_DIM + k0 + (c1 & 3) * 8, &lA[c1 * 8]);
    gload_lds16(Wb + (size_t)(n0 + (c0 >> 2)) * IN_DIM + k0 + (c0 & 3) * 8, &lB[c0 * 8]);
    gload_lds16(Wb + (size_t)(n0 + (c1 >> 2)) * IN_DIM + k0 + (c1 & 3) * 8, &lB[c1 * 8]);
    __syncthreads();  // drains vmcnt -> tiles visible
    bf16x8 af[4], bv[4];
#pragma unroll
    for (int i = 0; i < 4; i++) af[i] = *(const bf16x8*)&lA[(wr * 64 + i * 16 + fr) * 32 + fq * 8];
#pragma unroll
    for (int j = 0; j < 4; j++) bv[j] = *(const bf16x8*)&lB[(wc * 64 + j * 16 + fr) * 32 + fq * 8];
#pragma unroll
    for (int i = 0; i < 4; i++)
#pragma unroll
      for (int j = 0; j < 4; j++)
        acc[i][j] = __builtin_amdgcn_mfma_f32_16x16x32_bf16(af[i], bv[j], acc[i][j], 0, 0, 0);
    __syncthreads();  // reads done before next-stage overwrite
  }

  // epilogue: bias + RoPE + bf16 store
#pragma unroll
  for (int i = 0; i < 4; i++) {
    const int mb = m0 + wr * 64 + i * 16 + fq * 4;
#pragma unroll
    for (int j2 = 0; j2 < 4; j2++) {
      const int n = n0 + wc * 64 + j2 * 16 + fr;
      const float bvn = bias[n];
#pragma unroll
      for (int j = 0; j < 4; j++) {
        float v = acc[i][j2][j] + bvn;
        float p = __shfl_xor(v, 1);          // partner column n^1 (same rows)
        float rot = (n & 1) ? p : -p;        // d even: -x[d+1]; d odd: +x[d-1]
        const int m_ = mb + j;
        const int s = m_ & (SS - 1);
        const int d = n & (DHEAD - 1);
        float2 cs = rt[s * 128 + (d >> 1)];
        float o = v * cs.x + rot * cs.y;
        const int bidx = m_ >> 10;
        const int h = n >> 9, qk = (n >> 8) & 1;
        QK[(size_t)((bidx * 2 + h) * 2 + qk) * (SS * DHEAD) + s * DHEAD + d] = (bf16)o;
      }
    }
  }
}

// v4: swapped-operand MFMA (A=K, B=Q) -> lane owns m=m0+fr, n=n0+4*fq+j
// => int4 label/mask loads, contiguous 8-float logit stores per lane.
// Q (both heads) in regs; K streamed from L2; no LDS, no barriers.
__global__ __launch_bounds__(256, 3) void logits_loss_kernel(
    const bf16* __restrict__ QK, const int* __restrict__ labels,
    const int* __restrict__ masks, float* __restrict__ out,
    float* __restrict__ accbuf) {
  __shared__ float red[8];
  const int tid = threadIdx.x;
  const int lane = tid & 63, w = tid >> 6;
  const int fr = lane & 15, fq = lane >> 4;

  const int bid = blockIdx.x;          // 0..2047
  const int b = bid & 7;               // batch == XCD slot
  const int r = bid >> 3;              // 0..255
  const int m0 = (r & 63) * 16;        // m-tile (16 rows)
  const int nq = (r >> 6) * 256 + w * 64;  // wave's 64-row n-range (4 tiles)

  const size_t HS = (size_t)SS * DHEAD;
  const bf16* Qp0 = QK + (size_t)(b * 4 + 0) * HS + (size_t)(m0 + fr) * DHEAD + fq * 8;
  const bf16* Qp1 = QK + (size_t)(b * 4 + 2) * HS + (size_t)(m0 + fr) * DHEAD + fq * 8;
  const bf16* Kb0 = QK + (size_t)(b * 4 + 1) * HS + fq * 8;
  const bf16* Kb1 = QK + (size_t)(b * 4 + 3) * HS + fq * 8;

  // Q fragments (B-operand): 16 x bf16x8 = 64 VGPR, live whole kernel
  bf16x8 q0[8], q1[8];
#pragma unroll
  for (int kk = 0; kk < 8; kk++) {
    q0[kk] = *(const bf16x8*)(Qp0 + kk * 32);
    q1[kk] = *(const bf16x8*)(Qp1 + kk * 32);
  }

  const int m = m0 + fr;
  const size_t pbase = ((size_t)(b * SS + m)) * SS + nq + 4 * fq;  // 16B aligned

  float s_sum = 0.f, s_cnt = 0.f;
  int4 lab = *(const int4*)(labels + pbase);
  int4 msk = *(const int4*)(masks + pbase);

#pragma unroll
  for (int ni = 0; ni < 4; ++ni) {
    const int n0 = nq + ni * 16;
    const bf16* kr0 = Kb0 + (size_t)(n0 + fr) * DHEAD;
    const bf16* kr1 = Kb1 + (size_t)(n0 + fr) * DHEAD;
    f32x4 acc0 = {}, acc1 = {};
#pragma unroll
    for (int kk = 0; kk < 8; kk++)
      acc0 = __builtin_amdgcn_mfma_f32_16x16x32_bf16(*(const bf16x8*)(kr0 + kk * 32), q0[kk], acc0, 0, 0, 0);
#pragma unroll
    for (int kk = 0; kk < 8; kk++)
      acc1 = __builtin_amdgcn_mfma_f32_16x16x32_bf16(*(const bf16x8*)(kr1 + kk * 32), q1[kk], acc1, 0, 0, 0);

    int4 labn, mskn;
    if (ni < 3) {
      labn = *(const int4*)(labels + pbase + (ni + 1) * 16);
      mskn = *(const int4*)(masks + pbase + (ni + 1) * 16);
    }

    // lane owns m, n = n0+4*fq+j (j=0..3); acc0=head0, acc1=head1
    float* op = out + 2 * (pbase + (size_t)ni * 16);
    op[1] = acc0[0];
    *(float2*)(op + 2) = make_float2(acc1[0], acc0[1]);
    float4 v4; v4.x = acc1[1]; v4.y = acc0[2]; v4.z = acc1[2]; v4.w = acc0[3];
    *(float4*)(op + 4) = v4;
    op[8] = acc1[3];

    const int labv[4] = {lab.x, lab.y, lab.z, lab.w};
    const int mskv[4] = {msk.x, msk.y, msk.z, msk.w};
#pragma unroll
    for (int j = 0; j < 4; j++) {
      float l0 = acc0[j], l1 = acc1[j];
      float mk = (float)mskv[j];
      float z = labv[j] ? (l0 - l1) : (l1 - l0);   // l_other - l_label
      float mz = fmaxf(z, 0.f);
      s_sum += mk * (mz + __logf(__expf(-mz) + __expf(z - mz)));  // stable softplus
      s_cnt += mk;
    }
    lab = labn; msk = mskn;
  }

#pragma unroll
  for (int off = 32; off; off >>= 1) {
    s_sum += __shfl_down(s_sum, off);
    s_cnt += __shfl_down(s_cnt, off);
  }
  if (lane == 0) { red[w] = s_sum; red[4 + w] = s_cnt; }
  __syncthreads();
  if (tid == 0) {
    atomicAdd(&accbuf[0], red[0] + red[1] + red[2] + red[3]);
    atomicAdd(&accbuf[1], red[4] + red[5] + red[6] + red[7]);
  }
}

__global__ void finalize_kernel(const float* __restrict__ accbuf, float* __restrict__ out) {
  out[0] = accbuf[0] / accbuf[1];
}

extern "C" void kernel_launch(void* const* d_in, const int* in_sizes, int n_in,
                              void* d_out, int out_size, void* d_ws, size_t ws_size,
                              hipStream_t stream) {
  const float* X = (const float*)d_in[0];
  const int* labels = (const int*)d_in[1];
  const int* masks = (const int*)d_in[2];
  const float* W = (const float*)d_in[3];
  const float* bias = (const float*)d_in[4];
  float* out = (float*)d_out;
  char* ws = (char*)d_ws;

  bf16* QK = (bf16*)(ws + QK_OFF);
  bf16* Xb = (bf16*)(ws + XB_OFF);
  bf16* Wb = (bf16*)(ws + WB_OFF);
  float2* rt = (float2*)(ws + RT_OFF);
  float* acc = (float*)(ws + ACC_OFF);

  hipMemsetAsync(acc, 0, 8, stream);
  cvt_bf16_kernel<<<(MTOT * IN_DIM / 4 + 255) / 256, 256, 0, stream>>>(X, Xb, MTOT * IN_DIM / 4);
  cvt_bf16_kernel<<<(NOUT * IN_DIM / 4 + 255) / 256, 256, 0, stream>>>(W, Wb, NOUT * IN_DIM / 4);
  rope_table_kernel<<<(SS * 128) / 256, 256, 0, stream>>>(rt);
  gemm_rope_kernel<<<dim3(NOUT / 128, MTOT / 128), 256, 0, stream>>>(Xb, Wb, bias, rt, QK);
  logits_loss_kernel<<<2048, 256, 0, stream>>>(QK, labels, masks, out, acc);
  finalize_kernel<<<1, 1, 0, stream>>>(acc, out);
}

// Round 5
// 94.654 us; speedup vs baseline: 1.7942x; 1.7942x over previous
//
#include <hip/hip_runtime.h>
#include <hip/hip_bf16.h>

#define BB 8
#define SS 1024
#define IN_DIM 1024
#define NOUT 1024
#define DHEAD 256
#define MTOT (BB*SS)

typedef __bf16 bf16;
typedef __bf16 bf16x8 __attribute__((ext_vector_type(8)));
typedef __bf16 bf16x4 __attribute__((ext_vector_type(4)));
typedef float f32x4 __attribute__((ext_vector_type(4)));
typedef float f32x4u __attribute__((ext_vector_type(4), aligned(4)));  // 4B-aligned vec store

// ws layout (bytes)
#define QK_OFF   0                 // 8*2*2*1024*256 bf16 = 16 MiB
#define XB_OFF   (16u*1024*1024)   // 8192*1024 bf16     = 16 MiB
#define WB_OFF   (32u*1024*1024)   // 1024*1024 bf16     =  2 MiB
#define RT_OFF   (34u*1024*1024)   // 1024*128 float2    =  1 MiB
#define ACC_OFF  (35u*1024*1024)   // 1024 float2 partials

__device__ __forceinline__ void gload_lds16(const void* g, void* l) {
  __builtin_amdgcn_global_load_lds(
      (const __attribute__((address_space(1))) unsigned int*)g,
      (__attribute__((address_space(3))) unsigned int*)l, 16, 0, 0);
}

__global__ void cvt_bf16_kernel(const float* __restrict__ in, bf16* __restrict__ out, int n4) {
  int i = blockIdx.x * blockDim.x + threadIdx.x;
  if (i >= n4) return;
  float4 v = ((const float4*)in)[i];
  bf16x4 o;
  o.x = (bf16)v.x; o.y = (bf16)v.y; o.z = (bf16)v.z; o.w = (bf16)v.w;
  ((bf16x4*)out)[i] = o;
}

__global__ void rope_table_kernel(float2* __restrict__ rt) {
  int i = blockIdx.x * blockDim.x + threadIdx.x;   // S*128 = 131072
  int s = i >> 7, f = i & 127;
  float inv = __expf((float)f * (-2.70805020110221007f / 128.0f)); // 15^(-2f/256)
  float ang = (float)s * inv;
  float c, sn;
  __sincosf(ang, &sn, &c);
  rt[i] = make_float2(c, sn);
}

// C = X(bf16) @ W(bf16)^T + b, fused RoPE, write Q/K bf16 -> ws
// QK layout: [b][h][qk][s][d], qk: 0=Q 1=K
__global__ __launch_bounds__(256) void gemm_rope_kernel(
    const bf16* __restrict__ Xb, const bf16* __restrict__ Wb,
    const float* __restrict__ bias, const float2* __restrict__ rt,
    bf16* __restrict__ QK) {
  __shared__ __align__(16) bf16 lA[128 * 32];
  __shared__ __align__(16) bf16 lB[128 * 32];
  const int tid = threadIdx.x;
  const int lane = tid & 63, w = tid >> 6;
  const int wr = w >> 1, wc = w & 1;
  const int fr = lane & 15, fq = lane >> 4;
  const int m0 = blockIdx.y * 128, n0 = blockIdx.x * 128;
  const int c0 = tid, c1 = tid + 256;

  f32x4 acc[4][4] = {};

  for (int k0 = 0; k0 < IN_DIM; k0 += 32) {
    gload_lds16(Xb + (size_t)(m0 + (c0 >> 2)) * IN_DIM + k0 + (c0 & 3) * 8, &lA[c0 * 8]);
    gload_lds16(Xb + (size_t)(m0 + (c1 >> 2)) * IN_DIM + k0 + (c1 & 3) * 8, &lA[c1 * 8]);
    gload_lds16(Wb + (size_t)(n0 + (c0 >> 2)) * IN_DIM + k0 + (c0 & 3) * 8, &lB[c0 * 8]);
    gload_lds16(Wb + (size_t)(n0 + (c1 >> 2)) * IN_DIM + k0 + (c1 & 3) * 8, &lB[c1 * 8]);
    __syncthreads();  // drains vmcnt -> tiles visible
    bf16x8 af[4], bv[4];
#pragma unroll
    for (int i = 0; i < 4; i++) af[i] = *(const bf16x8*)&lA[(wr * 64 + i * 16 + fr) * 32 + fq * 8];
#pragma unroll
    for (int j = 0; j < 4; j++) bv[j] = *(const bf16x8*)&lB[(wc * 64 + j * 16 + fr) * 32 + fq * 8];
#pragma unroll
    for (int i = 0; i < 4; i++)
#pragma unroll
      for (int j = 0; j < 4; j++)
        acc[i][j] = __builtin_amdgcn_mfma_f32_16x16x32_bf16(af[i], bv[j], acc[i][j], 0, 0, 0);
    __syncthreads();  // reads done before next-stage overwrite
  }

  // epilogue: bias + RoPE + bf16 store
#pragma unroll
  for (int i = 0; i < 4; i++) {
    const int mb = m0 + wr * 64 + i * 16 + fq * 4;
#pragma unroll
    for (int j2 = 0; j2 < 4; j2++) {
      const int n = n0 + wc * 64 + j2 * 16 + fr;
      const float bvn = bias[n];
#pragma unroll
      for (int j = 0; j < 4; j++) {
        float v = acc[i][j2][j] + bvn;
        float p = __shfl_xor(v, 1);          // partner column n^1 (same rows)
        float rot = (n & 1) ? p : -p;        // d even: -x[d+1]; d odd: +x[d-1]
        const int m_ = mb + j;
        const int s = m_ & (SS - 1);
        const int d = n & (DHEAD - 1);
        float2 cs = rt[s * 128 + (d >> 1)];
        float o = v * cs.x + rot * cs.y;
        const int bidx = m_ >> 10;
        const int h = n >> 9, qk = (n >> 8) & 1;
        QK[(size_t)((bidx * 2 + h) * 2 + qk) * (SS * DHEAD) + s * DHEAD + d] = (bf16)o;
      }
    }
  }
}

// v5: LDS-staged (remat-proof), 128m x 64n x 2h per 256-thread block.
// Swapped MFMA (A=K, B=Q): lane owns m = col (fr), n = row (4*fq+j)
//   -> int4 label/mask loads + 16B logit stores.
// Grid 1024, bid&7 = batch -> XCD-local panels. No atomics (per-block partials).
__global__ __launch_bounds__(256, 4) void logits_loss_kernel(
    const bf16* __restrict__ QK, const int* __restrict__ labels,
    const int* __restrict__ masks, float* __restrict__ out,
    float2* __restrict__ part) {
  __shared__ __align__(16) bf16 lQ[2][128 * 32];
  __shared__ __align__(16) bf16 lK[2][64 * 32];
  __shared__ float red[8];
  const int tid = threadIdx.x;
  const int lane = tid & 63, w = tid >> 6;
  const int wr = w >> 1, wc = w & 1;
  const int fr = lane & 15, fq = lane >> 4;

  const int bid = blockIdx.x;     // 0..1023
  const int b = bid & 7;          // batch == XCD (round-robin dispatch)
  const int r = bid >> 3;         // 0..127
  const int m0 = (r & 7) * 128;   // m-tile within batch
  const int n0 = (r >> 3) * 64;   // n-tile

  const size_t HS = (size_t)SS * DHEAD;
  const bf16* Qh[2] = {QK + (size_t)(b * 4 + 0) * HS, QK + (size_t)(b * 4 + 2) * HS};
  const bf16* Kh[2] = {QK + (size_t)(b * 4 + 1) * HS, QK + (size_t)(b * 4 + 3) * HS};
  const int c0 = tid, c1 = tid + 256;

  f32x4 acc[2][4][2] = {};

  for (int k0 = 0; k0 < DHEAD; k0 += 32) {
#pragma unroll
    for (int h = 0; h < 2; ++h) {
      gload_lds16(Qh[h] + (size_t)(m0 + (c0 >> 2)) * DHEAD + k0 + (c0 & 3) * 8, &lQ[h][c0 * 8]);
      gload_lds16(Qh[h] + (size_t)(m0 + (c1 >> 2)) * DHEAD + k0 + (c1 & 3) * 8, &lQ[h][c1 * 8]);
      gload_lds16(Kh[h] + (size_t)(n0 + (c0 >> 2)) * DHEAD + k0 + (c0 & 3) * 8, &lK[h][c0 * 8]);
    }
    __syncthreads();  // drains vmcnt
#pragma unroll
    for (int h = 0; h < 2; ++h) {
      bf16x8 bq[4], ak[2];
#pragma unroll
      for (int mi = 0; mi < 4; mi++) bq[mi] = *(const bf16x8*)&lQ[h][(wr * 64 + mi * 16 + fr) * 32 + fq * 8];
#pragma unroll
      for (int nj = 0; nj < 2; nj++) ak[nj] = *(const bf16x8*)&lK[h][(wc * 32 + nj * 16 + fr) * 32 + fq * 8];
#pragma unroll
      for (int mi = 0; mi < 4; mi++)
#pragma unroll
        for (int nj = 0; nj < 2; nj++)
          acc[h][mi][nj] = __builtin_amdgcn_mfma_f32_16x16x32_bf16(ak[nj], bq[mi], acc[h][mi][nj], 0, 0, 0);
    }
    __syncthreads();
  }

  // epilogue: lane owns global row M (m), 4 consecutive n
  float s_sum = 0.f, s_cnt = 0.f;
#pragma unroll
  for (int mi = 0; mi < 4; mi++) {
    const int M = b * SS + m0 + wr * 64 + mi * 16 + fr;   // 0..8191
#pragma unroll
    for (int nj = 0; nj < 2; nj++) {
      const int n = n0 + wc * 32 + nj * 16 + 4 * fq;
      const size_t p = (size_t)M * SS + n;                // labels/masks flat idx
      int4 lab = *(const int4*)(labels + p);
      int4 msk = *(const int4*)(masks + p);
      f32x4 l0v = acc[0][mi][nj];
      f32x4 l1v = acc[1][mi][nj];
      f32x4u st0, st1;
      st0[0] = l0v[0]; st0[1] = l1v[0]; st0[2] = l0v[1]; st0[3] = l1v[1];
      st1[0] = l0v[2]; st1[1] = l1v[2]; st1[2] = l0v[3]; st1[3] = l1v[3];
      *(f32x4u*)(out + 1 + 2 * p) = st0;
      *(f32x4u*)(out + 1 + 2 * p + 4) = st1;
      const int labv[4] = {lab.x, lab.y, lab.z, lab.w};
      const int mskv[4] = {msk.x, msk.y, msk.z, msk.w};
#pragma unroll
      for (int j = 0; j < 4; j++) {
        float l0 = l0v[j], l1 = l1v[j];
        float mk = (float)mskv[j];                   // PAIR_POS_WEIGHT==1 -> wl = mask
        float z = labv[j] ? (l0 - l1) : (l1 - l0);   // l_other - l_label
        float mz = fmaxf(z, 0.f);
        s_sum += mk * (mz + __logf(__expf(-mz) + __expf(z - mz)));  // stable softplus
        s_cnt += mk;
      }
    }
  }

#pragma unroll
  for (int off = 32; off; off >>= 1) {
    s_sum += __shfl_down(s_sum, off);
    s_cnt += __shfl_down(s_cnt, off);
  }
  if (lane == 0) { red[w] = s_sum; red[4 + w] = s_cnt; }
  __syncthreads();
  if (tid == 0)
    part[bid] = make_float2(red[0] + red[1] + red[2] + red[3],
                            red[4] + red[5] + red[6] + red[7]);
}

__global__ __launch_bounds__(256) void finalize_kernel(const float2* __restrict__ part,
                                                       float* __restrict__ out) {
  __shared__ float red[8];
  const int tid = threadIdx.x;
  const int lane = tid & 63, w = tid >> 6;
  float s = 0.f, c = 0.f;
#pragma unroll
  for (int i = 0; i < 4; i++) {
    float2 v = part[tid + i * 256];
    s += v.x; c += v.y;
  }
#pragma unroll
  for (int off = 32; off; off >>= 1) {
    s += __shfl_down(s, off);
    c += __shfl_down(c, off);
  }
  if (lane == 0) { red[w] = s; red[4 + w] = c; }
  __syncthreads();
  if (tid == 0)
    out[0] = (red[0] + red[1] + red[2] + red[3]) /
             (red[4] + red[5] + red[6] + red[7]);
}

extern "C" void kernel_launch(void* const* d_in, const int* in_sizes, int n_in,
                              void* d_out, int out_size, void* d_ws, size_t ws_size,
                              hipStream_t stream) {
  const float* X = (const float*)d_in[0];
  const int* labels = (const int*)d_in[1];
  const int* masks = (const int*)d_in[2];
  const float* W = (const float*)d_in[3];
  const float* bias = (const float*)d_in[4];
  float* out = (float*)d_out;
  char* ws = (char*)d_ws;

  bf16* QK = (bf16*)(ws + QK_OFF);
  bf16* Xb = (bf16*)(ws + XB_OFF);
  bf16* Wb = (bf16*)(ws + WB_OFF);
  float2* rt = (float2*)(ws + RT_OFF);
  float2* part = (float2*)(ws + ACC_OFF);

  cvt_bf16_kernel<<<(MTOT * IN_DIM / 4 + 255) / 256, 256, 0, stream>>>(X, Xb, MTOT * IN_DIM / 4);
  cvt_bf16_kernel<<<(NOUT * IN_DIM / 4 + 255) / 256, 256, 0, stream>>>(W, Wb, NOUT * IN_DIM / 4);
  rope_table_kernel<<<(SS * 128) / 256, 256, 0, stream>>>(rt);
  gemm_rope_kernel<<<dim3(NOUT / 128, MTOT / 128), 256, 0, stream>>>(Xb, Wb, bias, rt, QK);
  logits_loss_kernel<<<1024, 256, 0, stream>>>(QK, labels, masks, out, part);
  finalize_kernel<<<1, 256, 0, stream>>>(part, out);
}

// Round 6
// 89.627 us; speedup vs baseline: 1.8948x; 1.0561x over previous
//
#include <hip/hip_runtime.h>
#include <hip/hip_bf16.h>

#define BB 8
#define SS 1024
#define IN_DIM 1024
#define NOUT 1024
#define DHEAD 256
#define MTOT (BB*SS)

typedef __bf16 bf16;
typedef __bf16 bf16x8 __attribute__((ext_vector_type(8)));
typedef __bf16 bf16x4 __attribute__((ext_vector_type(4)));
typedef float f32x4 __attribute__((ext_vector_type(4)));
typedef float f32x4u __attribute__((ext_vector_type(4), aligned(4)));  // 4B-aligned vec store

// ws layout (bytes)
#define QK_OFF   0                 // 8*2*2*1024*256 bf16 = 16 MiB
#define XB_OFF   (16u*1024*1024)   // 8192*1024 bf16     = 16 MiB
#define WB_OFF   (32u*1024*1024)   // 1024*1024 bf16     =  2 MiB
#define RT_OFF   (34u*1024*1024)   // 1024*128 float2    =  1 MiB
#define ACC_OFF  (35u*1024*1024)   // 8192 float2 partials

__device__ __forceinline__ void gload_lds16(const void* g, void* l) {
  __builtin_amdgcn_global_load_lds(
      (const __attribute__((address_space(1))) unsigned int*)g,
      (__attribute__((address_space(3))) unsigned int*)l, 16, 0, 0);
}

__global__ void cvt_bf16_kernel(const float* __restrict__ in, bf16* __restrict__ out, int n4) {
  int i = blockIdx.x * blockDim.x + threadIdx.x;
  if (i >= n4) return;
  float4 v = ((const float4*)in)[i];
  bf16x4 o;
  o.x = (bf16)v.x; o.y = (bf16)v.y; o.z = (bf16)v.z; o.w = (bf16)v.w;
  ((bf16x4*)out)[i] = o;
}

__global__ void rope_table_kernel(float2* __restrict__ rt) {
  int i = blockIdx.x * blockDim.x + threadIdx.x;   // S*128 = 131072
  int s = i >> 7, f = i & 127;
  float inv = __expf((float)f * (-2.70805020110221007f / 128.0f)); // 15^(-2f/256)
  float ang = (float)s * inv;
  float c, sn;
  __sincosf(ang, &sn, &c);
  rt[i] = make_float2(c, sn);
}

// C = X(bf16) @ W(bf16)^T + b, fused RoPE, write Q/K bf16 -> ws
// QK layout: [b][h][qk][s][d], qk: 0=Q 1=K
__global__ __launch_bounds__(256) void gemm_rope_kernel(
    const bf16* __restrict__ Xb, const bf16* __restrict__ Wb,
    const float* __restrict__ bias, const float2* __restrict__ rt,
    bf16* __restrict__ QK) {
  __shared__ __align__(16) bf16 lA[128 * 32];
  __shared__ __align__(16) bf16 lB[128 * 32];
  const int tid = threadIdx.x;
  const int lane = tid & 63, w = tid >> 6;
  const int wr = w >> 1, wc = w & 1;
  const int fr = lane & 15, fq = lane >> 4;
  const int m0 = blockIdx.y * 128, n0 = blockIdx.x * 128;
  const int c0 = tid, c1 = tid + 256;

  f32x4 acc[4][4] = {};

  for (int k0 = 0; k0 < IN_DIM; k0 += 32) {
    gload_lds16(Xb + (size_t)(m0 + (c0 >> 2)) * IN_DIM + k0 + (c0 & 3) * 8, &lA[c0 * 8]);
    gload_lds16(Xb + (size_t)(m0 + (c1 >> 2)) * IN_DIM + k0 + (c1 & 3) * 8, &lA[c1 * 8]);
    gload_lds16(Wb + (size_t)(n0 + (c0 >> 2)) * IN_DIM + k0 + (c0 & 3) * 8, &lB[c0 * 8]);
    gload_lds16(Wb + (size_t)(n0 + (c1 >> 2)) * IN_DIM + k0 + (c1 & 3) * 8, &lB[c1 * 8]);
    __syncthreads();  // drains vmcnt -> tiles visible
    bf16x8 af[4], bv[4];
#pragma unroll
    for (int i = 0; i < 4; i++) af[i] = *(const bf16x8*)&lA[(wr * 64 + i * 16 + fr) * 32 + fq * 8];
#pragma unroll
    for (int j = 0; j < 4; j++) bv[j] = *(const bf16x8*)&lB[(wc * 64 + j * 16 + fr) * 32 + fq * 8];
#pragma unroll
    for (int i = 0; i < 4; i++)
#pragma unroll
      for (int j = 0; j < 4; j++)
        acc[i][j] = __builtin_amdgcn_mfma_f32_16x16x32_bf16(af[i], bv[j], acc[i][j], 0, 0, 0);
    __syncthreads();  // reads done before next-stage overwrite
  }

  // epilogue: bias + RoPE + bf16 store
#pragma unroll
  for (int i = 0; i < 4; i++) {
    const int mb = m0 + wr * 64 + i * 16 + fq * 4;
#pragma unroll
    for (int j2 = 0; j2 < 4; j2++) {
      const int n = n0 + wc * 64 + j2 * 16 + fr;
      const float bvn = bias[n];
#pragma unroll
      for (int j = 0; j < 4; j++) {
        float v = acc[i][j2][j] + bvn;
        float p = __shfl_xor(v, 1);          // partner column n^1 (same rows)
        float rot = (n & 1) ? p : -p;        // d even: -x[d+1]; d odd: +x[d-1]
        const int m_ = mb + j;
        const int s = m_ & (SS - 1);
        const int d = n & (DHEAD - 1);
        float2 cs = rt[s * 128 + (d >> 1)];
        float o = v * cs.x + rot * cs.y;
        const int bidx = m_ >> 10;
        const int h = n >> 9, qk = (n >> 8) & 1;
        QK[(size_t)((bidx * 2 + h) * 2 + qk) * (SS * DHEAD) + s * DHEAD + d] = (bf16)o;
      }
    }
  }
}

// chunk swizzle: involution on 16B-chunk column within a row (2 bits),
// controlled by row bits -> 2-way (free) LDS bank pattern on frag reads.
__device__ __forceinline__ int swz(int r) { return (r & 3) ^ ((r >> 2) & 3); }

// v6: 64m x 64n x 2h per block, grid 2048 (bid&7 = batch -> XCD-local panels).
// 2-phase double-buffered K-loop (stage next before compute, 1 barrier/iter).
// Both-sides XOR chunk swizzle (linear LDS dest, pre-swizzled global source).
// Swapped MFMA (A=K, B=Q): lane owns m-row (fr), 4 consecutive n (4*fq+j)
//   -> int4 label/mask loads + 16B logit stores. Per-wave partials to ws.
__global__ __launch_bounds__(256, 5) void logits_loss_kernel(
    const bf16* __restrict__ QK, const int* __restrict__ labels,
    const int* __restrict__ masks, float* __restrict__ out,
    float2* __restrict__ part) {
  __shared__ __align__(16) bf16 lQ[2][2][64 * 32];  // [phase][head]
  __shared__ __align__(16) bf16 lK[2][2][64 * 32];
  const int tid = threadIdx.x;
  const int lane = tid & 63, w = tid >> 6;
  const int wr = w >> 1, wc = w & 1;
  const int fr = lane & 15, fq = lane >> 4;

  const int bid = blockIdx.x;     // 0..2047
  const int b = bid & 7;          // batch == XCD slot
  const int r = bid >> 3;         // 0..255
  const int m0 = (r & 15) * 64;
  const int n0 = (r >> 4) * 64;

  const size_t HS = (size_t)SS * DHEAD;
  const bf16* Qh[2] = {QK + (size_t)(b * 4 + 0) * HS, QK + (size_t)(b * 4 + 2) * HS};
  const bf16* Kh[2] = {QK + (size_t)(b * 4 + 1) * HS, QK + (size_t)(b * 4 + 3) * HS};

  // staging: thread t -> linear LDS slot t (row t>>2, chunk t&3),
  // global source chunk column pre-swizzled (involution)
  const int sr = tid >> 2, sc = tid & 3;
  const int csrc = (sc ^ swz(sr)) * 8;  // element offset of source chunk
  const size_t qoff = (size_t)(m0 + sr) * DHEAD + csrc;
  const size_t koff = (size_t)(n0 + sr) * DHEAD + csrc;

#define STAGE(ph, k0_)                                         \
  do {                                                         \
    gload_lds16(Qh[0] + qoff + (k0_), &lQ[ph][0][tid * 8]);    \
    gload_lds16(Qh[1] + qoff + (k0_), &lQ[ph][1][tid * 8]);    \
    gload_lds16(Kh[0] + koff + (k0_), &lK[ph][0][tid * 8]);    \
    gload_lds16(Kh[1] + koff + (k0_), &lK[ph][1][tid * 8]);    \
  } while (0)

  f32x4 acc[2][2][2] = {};

  STAGE(0, 0);
  __syncthreads();

  int cur = 0;
  for (int t = 0; t < 8; ++t) {
    if (t < 7) STAGE(cur ^ 1, (t + 1) * 32);   // prefetch next k-step
#pragma unroll
    for (int h = 0; h < 2; ++h) {
      bf16x8 bq[2], ak[2];
#pragma unroll
      for (int mi = 0; mi < 2; mi++) {
        const int R = wr * 32 + mi * 16 + fr;
        bq[mi] = *(const bf16x8*)&lQ[cur][h][R * 32 + (fq ^ swz(R)) * 8];
      }
#pragma unroll
      for (int nj = 0; nj < 2; nj++) {
        const int R = wc * 32 + nj * 16 + fr;
        ak[nj] = *(const bf16x8*)&lK[cur][h][R * 32 + (fq ^ swz(R)) * 8];
      }
#pragma unroll
      for (int mi = 0; mi < 2; mi++)
#pragma unroll
        for (int nj = 0; nj < 2; nj++)
          acc[h][mi][nj] = __builtin_amdgcn_mfma_f32_16x16x32_bf16(ak[nj], bq[mi], acc[h][mi][nj], 0, 0, 0);
    }
    __syncthreads();   // drains prefetch vmcnt + protects cur for overwrite
    cur ^= 1;
  }

  // epilogue: lane owns global row M, 4 consecutive n per fragment
  float s_sum = 0.f, s_cnt = 0.f;
#pragma unroll
  for (int mi = 0; mi < 2; mi++) {
    const int M = b * SS + m0 + wr * 32 + mi * 16 + fr;
#pragma unroll
    for (int nj = 0; nj < 2; nj++) {
      const int n = n0 + wc * 32 + nj * 16 + 4 * fq;
      const size_t p = (size_t)M * SS + n;
      int4 lab = *(const int4*)(labels + p);
      int4 msk = *(const int4*)(masks + p);
      f32x4 l0v = acc[0][mi][nj];
      f32x4 l1v = acc[1][mi][nj];
      f32x4u st0, st1;
      st0[0] = l0v[0]; st0[1] = l1v[0]; st0[2] = l0v[1]; st0[3] = l1v[1];
      st1[0] = l0v[2]; st1[1] = l1v[2]; st1[2] = l0v[3]; st1[3] = l1v[3];
      *(f32x4u*)(out + 1 + 2 * p) = st0;
      *(f32x4u*)(out + 1 + 2 * p + 4) = st1;
      const int labv[4] = {lab.x, lab.y, lab.z, lab.w};
      const int mskv[4] = {msk.x, msk.y, msk.z, msk.w};
#pragma unroll
      for (int j = 0; j < 4; j++) {
        float l0 = l0v[j], l1 = l1v[j];
        float mk = (float)mskv[j];                   // PAIR_POS_WEIGHT==1 -> wl = mask
        float z = labv[j] ? (l0 - l1) : (l1 - l0);   // l_other - l_label
        float mz = fmaxf(z, 0.f);
        s_sum += mk * (mz + __logf(__expf(-mz) + __expf(z - mz)));  // stable softplus
        s_cnt += mk;
      }
    }
  }

#pragma unroll
  for (int off = 32; off; off >>= 1) {
    s_sum += __shfl_down(s_sum, off);
    s_cnt += __shfl_down(s_cnt, off);
  }
  if (lane == 0) part[bid * 4 + w] = make_float2(s_sum, s_cnt);
}

__global__ __launch_bounds__(1024) void finalize_kernel(const float2* __restrict__ part,
                                                        float* __restrict__ out) {
  __shared__ float red[32];
  const int tid = threadIdx.x;
  const int lane = tid & 63, w = tid >> 6;
  float s = 0.f, c = 0.f;
#pragma unroll
  for (int i = 0; i < 8; i++) {
    float2 v = part[tid + i * 1024];
    s += v.x; c += v.y;
  }
#pragma unroll
  for (int off = 32; off; off >>= 1) {
    s += __shfl_down(s, off);
    c += __shfl_down(c, off);
  }
  if (lane == 0) { red[w] = s; red[16 + w] = c; }
  __syncthreads();
  if (tid == 0) {
    float ts = 0.f, tc = 0.f;
#pragma unroll
    for (int i = 0; i < 16; i++) { ts += red[i]; tc += red[16 + i]; }
    out[0] = ts / tc;
  }
}

extern "C" void kernel_launch(void* const* d_in, const int* in_sizes, int n_in,
                              void* d_out, int out_size, void* d_ws, size_t ws_size,
                              hipStream_t stream) {
  const float* X = (const float*)d_in[0];
  const int* labels = (const int*)d_in[1];
  const int* masks = (const int*)d_in[2];
  const float* W = (const float*)d_in[3];
  const float* bias = (const float*)d_in[4];
  float* out = (float*)d_out;
  char* ws = (char*)d_ws;

  bf16* QK = (bf16*)(ws + QK_OFF);
  bf16* Xb = (bf16*)(ws + XB_OFF);
  bf16* Wb = (bf16*)(ws + WB_OFF);
  float2* rt = (float2*)(ws + RT_OFF);
  float2* part = (float2*)(ws + ACC_OFF);

  cvt_bf16_kernel<<<(MTOT * IN_DIM / 4 + 255) / 256, 256, 0, stream>>>(X, Xb, MTOT * IN_DIM / 4);
  cvt_bf16_kernel<<<(NOUT * IN_DIM / 4 + 255) / 256, 256, 0, stream>>>(W, Wb, NOUT * IN_DIM / 4);
  rope_table_kernel<<<(SS * 128) / 256, 256, 0, stream>>>(rt);
  gemm_rope_kernel<<<dim3(NOUT / 128, MTOT / 128), 256, 0, stream>>>(Xb, Wb, bias, rt, QK);
  logits_loss_kernel<<<2048, 256, 0, stream>>>(QK, labels, masks, out, part);
  finalize_kernel<<<1, 1024, 0, stream>>>(part, out);
}